// Round 6
// baseline (331.627 us; speedup 1.0000x reference)
//
#include <hip/hip_runtime.h>
#include <cstdint>
#include <cstddef>

// Problem constants
constexpr int Bc = 4;
constexpr int Tc = 4096;
constexpr int Cc = 1024;
constexpr int Hc = 16;
constexpr int Dc = 64;
constexpr int Mc = Bc * Tc;        // 16384 rows
constexpr int N1c = 3 * Cc;        // 3072
constexpr int Kc = Cc;             // 1024
constexpr int KBc = Kc / 32;       // 32 k-tiles

typedef __bf16 bf16x8 __attribute__((ext_vector_type(8)));
typedef float  f32x4  __attribute__((ext_vector_type(4)));
typedef __attribute__((address_space(1))) uint32_t gu32;
typedef __attribute__((address_space(3))) uint32_t lu32;

__device__ __forceinline__ float bf2f(unsigned short u) {
    return __uint_as_float(((unsigned)u) << 16);
}
__device__ __forceinline__ unsigned short f2bf(float f) {
    unsigned u = __float_as_uint(f);
    u += 0x7FFF + ((u >> 16) & 1);   // round-to-nearest-even (finite values)
    return (unsigned short)(u >> 16);
}

__device__ __forceinline__ void load_lds16(const void* g, void* l) {
    // wave-uniform LDS base + lane*16; per-lane global address
    __builtin_amdgcn_global_load_lds((gu32*)(uintptr_t)g, (lu32*)(uintptr_t)l, 16, 0, 0);
}

// ============ packed-fragment layout ============
// A 16(rows)x32(k) tile = 512 bf16 = 64 lanes x 8 elems, contiguous in lane order.
// lane = fq*16 + fr  (fr = row&15, fq = (k&31)>>3), elem j = k&7.
// tile index: (row>>4)*KB + (k>>5). Wave fragment load = tile_base + lane*16B
// -> one coalesced b128 (global) or one conflict-free ds_read_b128 (LDS).

// ---------------- x fp32 [M][K] -> packed bf16 fragments ----------------
__global__ void convert_x_packed(const float* __restrict__ x,
                                 unsigned short* __restrict__ Ap) {
    const int w = threadIdx.x >> 6, lane = threadIdx.x & 63;
    const int t = blockIdx.x * 4 + w;          // tile id = mb*KB + kb
    const int mb = t >> 5, kb = t & 31;
    const int r = lane >> 2, c = lane & 3;
    const float* src = x + (size_t)(mb * 16 + r) * Kc + kb * 32 + c * 8;
    float4 f0 = *(const float4*)src;
    float4 f1 = *(const float4*)(src + 4);
    unsigned short u[8];
    u[0] = f2bf(f0.x); u[1] = f2bf(f0.y); u[2] = f2bf(f0.z); u[3] = f2bf(f0.w);
    u[4] = f2bf(f1.x); u[5] = f2bf(f1.y); u[6] = f2bf(f1.z); u[7] = f2bf(f1.w);
    *(uint4*)(Ap + (size_t)t * 512 + (c * 16 + r) * 8) = *(uint4*)u;
}

// ---------------- W fp32 [K][N] -> packed bf16 fragments (transposed) ----------------
__global__ void transpose_convert_packed(const float* __restrict__ W,
                                         unsigned short* __restrict__ Bp,
                                         int K, int N) {
    __shared__ float tile[32][33];
    const int tx = threadIdx.x, ty = threadIdx.y;
    const int n0 = blockIdx.x * 32, k0 = blockIdx.y * 32;
    for (int i = ty; i < 32; i += 8)
        tile[i][tx] = W[(size_t)(k0 + i) * N + n0 + tx];
    __syncthreads();
    const int t = ty * 32 + tx;
    const int h = t >> 7, rr = t & 127, lane = rr >> 1, half = rr & 1;
    const int fq = lane >> 4, fn = lane & 15;
    unsigned short u[4];
    #pragma unroll
    for (int j = 0; j < 4; ++j)
        u[j] = f2bf(tile[fq * 8 + half * 4 + j][h * 16 + fn]);
    size_t tileIdx = (size_t)((n0 >> 4) + h) * (K >> 5) + (k0 >> 5);
    *(uint2*)(Bp + tileIdx * 512 + lane * 8 + half * 4) = *(uint2*)u;
}

// ---------------- LDS-staged bf16 MFMA GEMM, BK=64 ----------------
// Packed-fragment LDS (conflict-free ds_read_b128). Per K=64 step:
// 8 global_load_lds(16B) per wave, one barrier pair, 2 k-sub-slices of
// 8 ds_read_b128 + 16 MFMA each (frags reloaded per slice to cap VGPRs).
// VSPLIT (GEMM1): cols >=2048 (the V third of qkv) are written per-token
// TRANSPOSED into vT[token][d*16+g] so attn's PV B-frags are direct b128 loads.
template <bool OUT_BF16, bool VSPLIT>
__global__ __launch_bounds__(256, 4) void lds_gemm_kernel(
    const unsigned short* __restrict__ Ap,
    const unsigned short* __restrict__ Bp,
    const float* __restrict__ bias,
    void* __restrict__ Cout,
    unsigned short* __restrict__ vT,
    int M, int N, int K, int NB) {
    __shared__ unsigned short sA[16 * 512];
    __shared__ unsigned short sB[16 * 512];
    const int KB  = K >> 5;            // 32-wide tiles along K
    const int KB2 = K >> 6;            // 64-wide K steps
    const int MB  = M >> 7;
    const int id   = blockIdx.x;
    const int xcd  = id & 7;
    const int per  = id >> 3;
    const int MSTR = MB >> 3;
    const int byl  = per & 7;
    const int bx   = (per >> 3) % NB;
    const int pass = per / (8 * NB);
    const int by   = xcd * MSTR + pass * 8 + byl;

    const int w    = threadIdx.x >> 6;
    const int lane = threadIdx.x & 63;
    const int m0 = by * 128;
    const int n0 = bx * 128;
    const int wm = (w >> 1) * 64;
    const int wn = (w & 1) * 64;

    // DMA: wave w stages A m-tiles {w, w+4} and B n-tiles {w, w+4}, both k-slices
    const unsigned short* gA0 = Ap + ((size_t)(by * 8 + w    ) * KB) * 512 + lane * 8;
    const unsigned short* gA1 = Ap + ((size_t)(by * 8 + w + 4) * KB) * 512 + lane * 8;
    const unsigned short* gB0 = Bp + ((size_t)(bx * 8 + w    ) * KB) * 512 + lane * 8;
    const unsigned short* gB1 = Bp + ((size_t)(bx * 8 + w + 4) * KB) * 512 + lane * 8;
    unsigned short* lA0 = sA + (w * 2) * 512;
    unsigned short* lA1 = sA + ((w + 4) * 2) * 512;
    unsigned short* lB0 = sB + (w * 2) * 512;
    unsigned short* lB1 = sB + ((w + 4) * 2) * 512;

    // fragment read pointers (linear in lane -> conflict-free)
    const unsigned short* aP = sA + ((wm >> 4) * 2) * 512 + lane * 8;
    const unsigned short* bP = sB + ((wn >> 4) * 2) * 512 + lane * 8;

    const f32x4 zero4 = {0.f, 0.f, 0.f, 0.f};
    f32x4 acc[4][4];
    #pragma unroll
    for (int i = 0; i < 4; ++i)
        #pragma unroll
        for (int j = 0; j < 4; ++j) acc[i][j] = zero4;

    #pragma unroll 1
    for (int kb = 0; kb < KB2; ++kb) {
        load_lds16(gA0,       lA0);
        load_lds16(gA0 + 512, lA0 + 512);
        load_lds16(gA1,       lA1);
        load_lds16(gA1 + 512, lA1 + 512);
        load_lds16(gB0,       lB0);
        load_lds16(gB0 + 512, lB0 + 512);
        load_lds16(gB1,       lB1);
        load_lds16(gB1 + 512, lB1 + 512);
        gA0 += 1024; gA1 += 1024; gB0 += 1024; gB1 += 1024;
        __syncthreads();   // drains DMA (vmcnt) + aligns waves

        #pragma unroll
        for (int ks = 0; ks < 2; ++ks) {
            bf16x8 af[4], bfr[4];
            #pragma unroll
            for (int mi = 0; mi < 4; ++mi)
                af[mi]  = *(const bf16x8*)(aP + (mi * 2 + ks) * 512);
            #pragma unroll
            for (int ni = 0; ni < 4; ++ni)
                bfr[ni] = *(const bf16x8*)(bP + (ni * 2 + ks) * 512);
            #pragma unroll
            for (int mi = 0; mi < 4; ++mi)
                #pragma unroll
                for (int ni = 0; ni < 4; ++ni)
                    acc[mi][ni] = __builtin_amdgcn_mfma_f32_16x16x32_bf16(
                        af[mi], bfr[ni], acc[mi][ni], 0, 0, 0);
        }
        __syncthreads();   // LDS consumed before next staging overwrites
    }

    // epilogue: D row = (lane>>4)*4 + reg, col = lane&15
    const int fr = lane & 15;
    const int fq = lane >> 4;
    #pragma unroll
    for (int mi = 0; mi < 4; ++mi) {
        #pragma unroll
        for (int ni = 0; ni < 4; ++ni) {
            int row = m0 + wm + mi * 16 + fq * 4;
            int col = n0 + wn + ni * 16 + fr;
            float bb = bias[col];
            if (VSPLIT && col >= 2048) {
                int g = (col - 2048) >> 6, d = (col - 2048) & 63;
                #pragma unroll
                for (int r = 0; r < 4; ++r)
                    vT[(size_t)(row + r) * 1024 + d * 16 + g] = f2bf(acc[mi][ni][r] + bb);
            } else {
                #pragma unroll
                for (int r = 0; r < 4; ++r) {
                    float v = acc[mi][ni][r] + bb;
                    if (OUT_BF16)
                        ((unsigned short*)Cout)[(size_t)(row + r) * N + col] = f2bf(v);
                    else
                        ((float*)Cout)[(size_t)(row + r) * N + col] = v;
                }
            }
        }
    }
}

// ---------------- per-token head-axis attention, MFMA, packed-fragment out ----------------
// One wave per token. Q,K fragments and V^T fragments ALL direct b128 global
// loads (vT pre-transposed by GEMM1's epilogue). Only LDS use: P round-trip.
__global__ __launch_bounds__(256) void attn_mfma_kernel(
    const unsigned short* __restrict__ qkv,
    const unsigned short* __restrict__ vT,
    unsigned short* __restrict__ attP) {
    __shared__ float sPm[4][16 * 20];
    const int w    = threadIdx.x >> 6;
    const int lane = threadIdx.x & 63;
    const int m    = lane & 15;
    const int q    = lane >> 4;
    const int row  = blockIdx.x * 4 + w;
    float* sP = sPm[w];

    const unsigned short* src = qkv + (size_t)row * 3072;

    // Q/K A/B fragments straight from global
    bf16x8 aq0 = *(const bf16x8*)(src + m * 64 + q * 8);
    bf16x8 aq1 = *(const bf16x8*)(src + m * 64 + 32 + q * 8);
    bf16x8 bk0 = *(const bf16x8*)(src + 1024 + m * 64 + q * 8);
    bf16x8 bk1 = *(const bf16x8*)(src + 1024 + m * 64 + 32 + q * 8);

    // V^T B-fragments straight from global: vt[c4] lane holds V[g=q*8+j][c4*16+m].
    // q>=2 reads adjacent garbage (finite) — annihilated by zeroed P quads.
    const unsigned short* vsrc = vT + (size_t)row * 1024;
    bf16x8 vt[4];
    #pragma unroll
    for (int c4 = 0; c4 < 4; ++c4)
        vt[c4] = *(const bf16x8*)(vsrc + (c4 * 16 + m) * 16 + q * 8);

    // scores: S[h][g] = q[h]·k[g]
    f32x4 s = {0.f, 0.f, 0.f, 0.f};
    s = __builtin_amdgcn_mfma_f32_16x16x32_bf16(aq0, bk0, s, 0, 0, 0);
    s = __builtin_amdgcn_mfma_f32_16x16x32_bf16(aq1, bk1, s, 0, 0, 0);

    // softmax over g (= lane&15) per row h=q*4+r; P -> LDS fp32
    #pragma unroll
    for (int r = 0; r < 4; ++r) {
        float t0 = s[r] * 0.125f;          // 1/sqrt(64)
        float mx = t0;
        mx = fmaxf(mx, __shfl_xor(mx, 1));
        mx = fmaxf(mx, __shfl_xor(mx, 2));
        mx = fmaxf(mx, __shfl_xor(mx, 4));
        mx = fmaxf(mx, __shfl_xor(mx, 8));
        float e = __expf(t0 - mx);
        float su = e;
        su += __shfl_xor(su, 1);
        su += __shfl_xor(su, 2);
        su += __shfl_xor(su, 4);
        su += __shfl_xor(su, 8);
        sP[(q * 4 + r) * 20 + m] = e / su;
    }
    __syncthreads();

    // P A-fragment: lane holds P[h=m][g=quad*8+j]; quads 2,3 -> zero (K pad 16->32)
    const float* pr = sP + m * 20 + (q & 1) * 8;
    float4 pf0 = *(const float4*)(pr);
    float4 pf1 = *(const float4*)(pr + 4);
    const bool act = (q < 2);
    union { unsigned short u[8]; bf16x8 b; } pa;
    pa.u[0] = act ? f2bf(pf0.x) : 0;
    pa.u[1] = act ? f2bf(pf0.y) : 0;
    pa.u[2] = act ? f2bf(pf0.z) : 0;
    pa.u[3] = act ? f2bf(pf0.w) : 0;
    pa.u[4] = act ? f2bf(pf1.x) : 0;
    pa.u[5] = act ? f2bf(pf1.y) : 0;
    pa.u[6] = act ? f2bf(pf1.z) : 0;
    pa.u[7] = act ? f2bf(pf1.w) : 0;

    // PV: out[h][d] = sum_g P[h][g] V[g][d]; write packed-fragment layout
    const size_t tileBase = (size_t)(row >> 4) * 32 * 512;   // token's m-block (KB=32)
    const int fr_tok = row & 15;
    #pragma unroll
    for (int c4 = 0; c4 < 4; ++c4) {
        f32x4 o = {0.f, 0.f, 0.f, 0.f};
        o = __builtin_amdgcn_mfma_f32_16x16x32_bf16(pa.b, vt[c4], o, 0, 0, 0);
        #pragma unroll
        for (int r = 0; r < 4; ++r) {
            int col = (q * 4 + r) * 64 + c4 * 16 + m;        // k index in [0,1024)
            size_t off = tileBase + (size_t)(col >> 5) * 512
                       + (((col >> 3) & 3) * 16 + fr_tok) * 8 + (col & 7);
            attP[off] = f2bf(o[r]);
        }
    }
}

extern "C" void kernel_launch(void* const* d_in, const int* in_sizes, int n_in,
                              void* d_out, int out_size, void* d_ws, size_t ws_size,
                              hipStream_t stream) {
    const float* x    = (const float*)d_in[0];
    const float* Wqkv = (const float*)d_in[1];
    const float* bqkv = (const float*)d_in[2];
    const float* Wout = (const float*)d_in[3];
    const float* bout = (const float*)d_in[4];
    float* out = (float*)d_out;

    // workspace: xp 32M | Wqkv_p 6M | Wout_p 2M | qkv 96M | vT 32M = ~168 MB
    char* ws = (char*)d_ws;
    unsigned short* xp   = (unsigned short*)ws;                 ws += (size_t)Mc * Kc * 2;
    unsigned short* Wqkp = (unsigned short*)ws;                 ws += (size_t)N1c * Kc * 2;
    unsigned short* Wop  = (unsigned short*)ws;                 ws += (size_t)Cc * Kc * 2;
    unsigned short* qkv  = (unsigned short*)ws;                 ws += (size_t)Mc * N1c * 2;
    unsigned short* vT   = (unsigned short*)ws;
    unsigned short* attP = xp;   // alias: xp dead after GEMM1

    // 1) x -> packed bf16 fragments
    convert_x_packed<<<(Mc / 16) * KBc / 4, 256, 0, stream>>>(x, xp);
    // 2) weights -> packed bf16 fragments (transposed)
    transpose_convert_packed<<<dim3(N1c / 32, Kc / 32), dim3(32, 8), 0, stream>>>(Wqkv, Wqkp, Kc, N1c);
    transpose_convert_packed<<<dim3(Cc / 32, Kc / 32), dim3(32, 8), 0, stream>>>(Wout, Wop, Kc, Cc);
    // 3) qkv = x @ W_qkv + b_qkv   (Q,K row-major bf16; V transposed into vT)
    lds_gemm_kernel<true, true><<<(N1c / 128) * (Mc / 128), 256, 0, stream>>>(
        xp, Wqkp, bqkv, qkv, vT, Mc, N1c, Kc, N1c / 128);
    // 4) head-axis attention per token (MFMA), writes packed-fragment A
    attn_mfma_kernel<<<Mc / 4, 256, 0, stream>>>(qkv, vT, attP);
    // 5) out = att @ W_out + b_out (fp32 row-major out)
    lds_gemm_kernel<false, false><<<(Cc / 128) * (Mc / 128), 256, 0, stream>>>(
        attP, Wop, bout, out, nullptr, Mc, Cc, Kc, Cc / 128);
}